// Round 13
// baseline (245.037 us; speedup 1.0000x reference)
//
#include <hip/hip_runtime.h>

// OnLSTMCell fused pipeline for MI355X (gfx950).
// B=8192, input=1024, hidden=1024, level=64, d_in=2048.
// ws layout (bytes), total ~117 MB:
//   A_HI   @ 0          : u16[8192*2048]  (32 MB)   bf16(concat(input,h_prev))
//   A_LO   @ 33554432   : u16[8192*2048]  (32 MB)   bf16 residual (level path precision)
//   W_HI   @ 67108864   : u16[4224*2048]  (16.5 MB) rows 0..4095 gate-interleaved (n=j*4+gate), 4096..4223 = W_level
//   WLEV_LO@ 84410368   : u16[128*2048]   (0.5 MB)
//   PART   @ 84934656   : f32[8][8192][128] (32 MB) split-K partials of level GEMM
//   IH     @ 118489088  : f32[8192*64]    (2 MB)
//   FH     @ 120586240  : f32[8192*64]    (2 MB)

typedef unsigned short u16;
typedef __attribute__((ext_vector_type(8))) short bf16x8;
typedef __attribute__((ext_vector_type(8))) short s8v;
typedef __attribute__((ext_vector_type(4))) float f32x4;
typedef __attribute__((ext_vector_type(4))) float v4f;

#define GLDS(g, l) __builtin_amdgcn_global_load_lds(                      \
    (const __attribute__((address_space(1))) void*)(g),                   \
    (__attribute__((address_space(3))) void*)(l), 16, 0, 0)

__device__ __forceinline__ u16 f2bf(float x) {
  unsigned u = __builtin_bit_cast(unsigned, x);
  u += 0x7FFFu + ((u >> 16) & 1u);
  return (u16)(u >> 16);
}
__device__ __forceinline__ float bf2f(u16 h) {
  unsigned u = ((unsigned)h) << 16;
  return __builtin_bit_cast(float, u);
}
__device__ __forceinline__ float fsig(float x) { return 1.0f / (1.0f + __expf(-x)); }
__device__ __forceinline__ float ftanhf(float x) { float e = __expf(2.0f * x); return 1.0f - 2.0f / (e + 1.0f); }

// ---------------------------------------------------------------- convert ---
__global__ __launch_bounds__(256) void k_convert(
    const float* __restrict__ inp, const float* __restrict__ hprev,
    const float* __restrict__ wl, const float* __restrict__ wlev,
    u16* __restrict__ Ahi, u16* __restrict__ Alo,
    u16* __restrict__ Whi, u16* __restrict__ Wlo)
{
  const int GA = (8192 * 2048) / 8;
  const int GW = (4224 * 2048) / 8;
  for (int gi = blockIdx.x * 256 + threadIdx.x; gi < GA + GW; gi += gridDim.x * 256) {
    if (gi < GA) {
      int e = gi << 3; int row = e >> 11, col = e & 2047;
      const float* src = (col < 1024) ? (inp + row * 1024 + col)
                                      : (hprev + row * 1024 + (col - 1024));
      v4f a = *(const v4f*)src, b = *(const v4f*)(src + 4);
      float vv[8] = {a.x, a.y, a.z, a.w, b.x, b.y, b.z, b.w};
      s8v hi, lo;
#pragma unroll
      for (int j = 0; j < 8; ++j) {
        u16 h = f2bf(vv[j]);
        hi[j] = (short)h;
        lo[j] = (short)f2bf(vv[j] - bf2f(h));
      }
      *(s8v*)(Ahi + e) = hi;
      *(s8v*)(Alo + e) = lo;
    } else {
      int e = (gi - GA) << 3; int n = e >> 11, k = e & 2047;
      const float* src;
      if (n < 4096) { int j = n >> 2, g = n & 3; src = wl + (size_t)((g << 10) | j) * 2048 + k; }
      else          { src = wlev + (size_t)(n - 4096) * 2048 + k; }
      v4f a = *(const v4f*)src, b = *(const v4f*)(src + 4);
      float vv[8] = {a.x, a.y, a.z, a.w, b.x, b.y, b.z, b.w};
      s8v hi, lo;
#pragma unroll
      for (int j = 0; j < 8; ++j) {
        u16 h = f2bf(vv[j]);
        hi[j] = (short)h;
        lo[j] = (short)f2bf(vv[j] - bf2f(h));
      }
      *(s8v*)(Whi + e) = hi;
      if (n >= 4096) *(s8v*)(Wlo + (size_t)(n - 4096) * 2048 + k) = lo;
    }
  }
}

// ----------------------------------------------- level GEMM (split-bf16) ---
__global__ __launch_bounds__(256) void k_gemm_level(
    const u16* __restrict__ Ahi, const u16* __restrict__ Alo,
    const u16* __restrict__ Whi, const u16* __restrict__ Wlo,
    float* __restrict__ part)
{
  __shared__ __align__(16) u16 smem[4 * 8192];
  u16 *Ah = smem, *Al = smem + 8192, *Bh = smem + 16384, *Bl = smem + 24576;
  const int tid = threadIdx.x, lane = tid & 63, wid = tid >> 6;
  const int wm = wid >> 1, wn = wid & 1;
  const int rm = blockIdx.x, s = blockIdx.y;
  const int lrow = lane >> 3, lcolE = (lane & 7) << 3;
  const int c16 = lane & 15, r16 = lane >> 4;
  f32x4 acc[4][4] = {};
  const u16* aBaseH = Ahi + (size_t)(rm << 7) * 2048;
  const u16* aBaseL = Alo + (size_t)(rm << 7) * 2048;
  const u16* bBaseH = Whi + (size_t)4096 * 2048;

  for (int kt = 0; kt < 4; ++kt) {
    const int k0 = (s << 8) + (kt << 6);
#pragma unroll
    for (int q = 0; q < 4; ++q) {
      const int ca = (wid << 2) + q;
      size_t roff = (size_t)((ca << 3) + lrow) * 2048 + k0 + lcolE;
      GLDS(aBaseH + roff, Ah + (ca << 9));
      GLDS(aBaseL + roff, Al + (ca << 9));
      GLDS(bBaseH + roff, Bh + (ca << 9));
      GLDS(Wlo + roff,    Bl + (ca << 9));
    }
    __syncthreads();
#pragma unroll
    for (int ks = 0; ks < 2; ++ks) {
      bf16x8 ah[4], al[4];
#pragma unroll
      for (int i = 0; i < 4; ++i) {
        int off = ((wm << 6) + (i << 4) + c16) * 64 + (ks << 5) + (r16 << 3);
        ah[i] = *(const bf16x8*)(Ah + off);
        al[i] = *(const bf16x8*)(Al + off);
      }
#pragma unroll
      for (int j = 0; j < 4; ++j) {
        int off = ((wn << 6) + (j << 4) + c16) * 64 + (ks << 5) + (r16 << 3);
        bf16x8 bh = *(const bf16x8*)(Bh + off);
        bf16x8 bl = *(const bf16x8*)(Bl + off);
#pragma unroll
        for (int i = 0; i < 4; ++i) {
          acc[i][j] = __builtin_amdgcn_mfma_f32_16x16x32_bf16(ah[i], bh, acc[i][j], 0, 0, 0);
          acc[i][j] = __builtin_amdgcn_mfma_f32_16x16x32_bf16(al[i], bh, acc[i][j], 0, 0, 0);
          acc[i][j] = __builtin_amdgcn_mfma_f32_16x16x32_bf16(ah[i], bl, acc[i][j], 0, 0, 0);
        }
      }
    }
    __syncthreads();
  }
#pragma unroll
  for (int mi = 0; mi < 4; ++mi)
#pragma unroll
    for (int ni = 0; ni < 4; ++ni)
#pragma unroll
      for (int r = 0; r < 4; ++r) {
        int ml = (wm << 6) + (mi << 4) + (r16 << 2) + r;
        int nl = (wn << 6) + (ni << 4) + c16;
        part[(size_t)((s << 13) + (rm << 7) + ml) * 128 + nl] = acc[mi][ni][r];
      }
}

// ------------------------------------------- softmax + cumsums (per row) ---
__global__ __launch_bounds__(256) void k_softmax(
    const float* __restrict__ part, float* __restrict__ ih, float* __restrict__ fh)
{
  const int tid = threadIdx.x, lane = tid & 63, w = tid >> 6;
  const int row = blockIdx.x * 4 + w;
  float vi = 0.f, vf = 0.f;
#pragma unroll
  for (int s = 0; s < 8; ++s) {
    vi += part[(size_t)((s << 13) + row) * 128 + lane];
    vf += part[(size_t)((s << 13) + row) * 128 + 64 + lane];
  }
  float mi = vi, mf = vf;
#pragma unroll
  for (int d = 1; d < 64; d <<= 1) {
    mi = fmaxf(mi, __shfl_xor(mi, d, 64));
    mf = fmaxf(mf, __shfl_xor(mf, d, 64));
  }
  float ei = __expf(vi - mi), ef = __expf(vf - mf);
  float si = ei, sf = ef;
#pragma unroll
  for (int d = 1; d < 64; d <<= 1) {
    si += __shfl_xor(si, d, 64);
    sf += __shfl_xor(sf, d, 64);
  }
  float pi = ei / si, pf = ef / sf;
  float ci = pi, cf = pf;
#pragma unroll
  for (int d = 1; d < 64; d <<= 1) {
    float t = __shfl_up(ci, d, 64); if (lane >= d) ci += t;
    float u = __shfl_up(cf, d, 64); if (lane >= d) cf += u;
  }
  ih[(row << 6) + lane] = 1.0f - (ci - pi);
  fh[(row << 6) + lane] = cf;
}

// -------------------------------------- main gates GEMM + fused epilogue ---
// SOFTWARE-PIPELINED register double-buffer (the r12 fix): per slice s,
// issue the 12 ds_reads for slice s+1 (slot already valid: vmcnt forced
// stage(s+1) one slice ago) BEFORE the 32 MFMAs of slice s, into the other
// register bank (X/Y). NO hand lgkmcnt(0): the compiler emits a COUNTED
// lgkm before the MFMAs (m97-verified), so reads(s+1) complete under
// MFMA(s) -> LDS pipe and MFMA pipe overlap instead of serializing
// (r12 = 66us MFMA + 73us LDS fully serial).
// Geometry: 256 thr = 4 waves (2M x 2N), wave-tile 128x64 (acc[8][4]=128
// VGPR; X+Y operand banks 96; ~245 total -> 2 waves/SIMD). Block 256x128,
// 3-slot 72KB LDS -> 2 blocks/CU. MFMA:ds_read = 32:12 = 2.67.
// Staging: 6 GLDS/slice/wave (A 4 chunks of 64 rows, B 2). vmcnt ledger:
// at slice s after STAGE6(s+2): outstanding = stage(s+1)(6) + stage(s+2)(6)
// -> vmcnt(6) forces stage(s+1) BEFORE this slice's barrier, which precedes
// reads(s+1). WAR: stage(s+2) overwrites slot (s-1)%3; reads(s-1) were
// drained before MFMA(s-1) (compiler lgkm) in every wave, and stage(s+2)
// is issued after the s-1 end-barrier. vmcnt(0) only at peeled s=62.
// Unroll-6 (3 slots x 2 reg banks); slices 60..63 peeled.
__global__ __launch_bounds__(256, 2) void k_gemm_main(
    const u16* __restrict__ Ab, const u16* __restrict__ Wb,
    const float* __restrict__ cprev, const float* __restrict__ ihp,
    const float* __restrict__ fhp, float* __restrict__ out)
{
  __shared__ __align__(16) u16 smem[36864];        // 72 KB; epi reuses 64 KB
  const int tid = threadIdx.x, lane = tid & 63, wid = tid >> 6;
  const int wm = wid >> 1, wn = wid & 1;           // 2M x 2N wave grid
  const int c16 = lane & 15, r16 = lane >> 4;

  // cm-FAST XCD swizzle (r3/r9-proven): 1024 blocks = 8 XCD x 128 =
  // 4 rm-panels (A L2-resident) x 32 cm (W streamed, L3-absorbed).
  const int bx = blockIdx.x;
  const int nb = (bx & 7) * 128 + (bx >> 3);
  const int rm = nb >> 5, cm = nb & 31;            // rm slow, cm fast

  // staging: thread -> (row sr=tid>>2 in 0..63 per 64-row chunk, slot
  // slq=tid&3); source pre-permuted (slq ^ (sr>>1)&3) -> linear GLDS dest.
  const int sr = tid >> 2;
  const int slq = tid & 3;
  const int xk = (slq ^ ((sr >> 1) & 3)) << 3;
  const u16* pa = Ab + (size_t)(rm * 256 + sr) * 2048 + xk;
  const u16* pb = Wb + (size_t)(cm * 128 + sr) * 2048 + xk;
  char* const ldsW = (char*)smem + (wid << 10);    // wave base within chunk

  // ds_read offsets (u16 elements): row*32 + swizzled 16B slot.
  const int xsl = (r16 ^ ((c16 >> 1) & 3)) << 3;
  const int base_a = (wm * 128 + c16) * 32 + xsl;        // + i*512 (i=0..7)
  const int base_b = 8192 + (wn * 64 + c16) * 32 + xsl;  // + j*512 (j=0..3)

  f32x4 acc[8][4] = {};
  bf16x8 aX0, aX1, aX2, aX3, aX4, aX5, aX6, aX7, bX0, bX1, bX2, bX3;
  bf16x8 aY0, aY1, aY2, aY3, aY4, aY5, aY6, aY7, bY0, bY1, bY2, bY3;

#define STAGE6(slice, slot) do {                                       \
    const u16* sa_ = pa + (slice) * 32;                                \
    const u16* sb_ = pb + (slice) * 32;                                \
    char* d_ = ldsW + (slot) * 24576;                                  \
    GLDS(sa_,          d_);                                            \
    GLDS(sa_ + 131072, d_ + 4096);                                     \
    GLDS(sa_ + 262144, d_ + 8192);                                     \
    GLDS(sa_ + 393216, d_ + 12288);                                    \
    GLDS(sb_,          d_ + 16384);                                    \
    GLDS(sb_ + 131072, d_ + 20480);                                    \
  } while (0)

#define READX(slot) do {                                               \
    const u16* p_ = smem + (slot) * 12288;                             \
    aX0 = *(const bf16x8*)(p_ + base_a);                               \
    aX1 = *(const bf16x8*)(p_ + base_a + 512);                         \
    aX2 = *(const bf16x8*)(p_ + base_a + 1024);                        \
    aX3 = *(const bf16x8*)(p_ + base_a + 1536);                        \
    aX4 = *(const bf16x8*)(p_ + base_a + 2048);                        \
    aX5 = *(const bf16x8*)(p_ + base_a + 2560);                        \
    aX6 = *(const bf16x8*)(p_ + base_a + 3072);                        \
    aX7 = *(const bf16x8*)(p_ + base_a + 3584);                        \
    bX0 = *(const bf16x8*)(p_ + base_b);                               \
    bX1 = *(const bf16x8*)(p_ + base_b + 512);                         \
    bX2 = *(const bf16x8*)(p_ + base_b + 1024);                        \
    bX3 = *(const bf16x8*)(p_ + base_b + 1536);                        \
  } while (0)

#define READY(slot) do {                                               \
    const u16* p_ = smem + (slot) * 12288;                             \
    aY0 = *(const bf16x8*)(p_ + base_a);                               \
    aY1 = *(const bf16x8*)(p_ + base_a + 512);                         \
    aY2 = *(const bf16x8*)(p_ + base_a + 1024);                        \
    aY3 = *(const bf16x8*)(p_ + base_a + 1536);                        \
    aY4 = *(const bf16x8*)(p_ + base_a + 2048);                        \
    aY5 = *(const bf16x8*)(p_ + base_a + 2560);                        \
    aY6 = *(const bf16x8*)(p_ + base_a + 3072);                        \
    aY7 = *(const bf16x8*)(p_ + base_a + 3584);                        \
    bY0 = *(const bf16x8*)(p_ + base_b);                               \
    bY1 = *(const bf16x8*)(p_ + base_b + 512);                         \
    bY2 = *(const bf16x8*)(p_ + base_b + 1024);                        \
    bY3 = *(const bf16x8*)(p_ + base_b + 1536);                        \
  } while (0)

#define MM1(i_, A_)                                                    \
    acc[i_][0] = __builtin_amdgcn_mfma_f32_16x16x32_bf16(A_, b_0, acc[i_][0], 0, 0, 0); \
    acc[i_][1] = __builtin_amdgcn_mfma_f32_16x16x32_bf16(A_, b_1, acc[i_][1], 0, 0, 0); \
    acc[i_][2] = __builtin_amdgcn_mfma_f32_16x16x32_bf16(A_, b_2, acc[i_][2], 0, 0, 0); \
    acc[i_][3] = __builtin_amdgcn_mfma_f32_16x16x32_bf16(A_, b_3, acc[i_][3], 0, 0, 0);

#define MFMAX() do {                                                   \
    bf16x8 b_0 = bX0, b_1 = bX1, b_2 = bX2, b_3 = bX3;                 \
    MM1(0, aX0) MM1(1, aX1) MM1(2, aX2) MM1(3, aX3)                    \
    MM1(4, aX4) MM1(5, aX5) MM1(6, aX6) MM1(7, aX7)                    \
  } while (0)

#define MFMAY() do {                                                   \
    bf16x8 b_0 = bY0, b_1 = bY1, b_2 = bY2, b_3 = bY3;                 \
    MM1(0, aY0) MM1(1, aY1) MM1(2, aY2) MM1(3, aY3)                    \
    MM1(4, aY4) MM1(5, aY5) MM1(6, aY6) MM1(7, aY7)                    \
  } while (0)

#define VM6() asm volatile("s_waitcnt vmcnt(6)" ::: "memory")
#define VM0() asm volatile("s_waitcnt vmcnt(0)" ::: "memory")
#define BAR() __builtin_amdgcn_s_barrier()

  // prologue: stage slices 0,1 -> slots 0,1; vmcnt(6) forces slice 0;
  // publish; preload reads(0) into X.
  STAGE6(0, 0); STAGE6(1, 1);
  VM6();
  BAR();
  READX(0);

  for (int u = 0; u < 10; ++u) {                   // slices 0..59
    const int s0 = u * 6;
    STAGE6(s0 + 2, 2); VM6(); BAR(); READY(1); MFMAX(); BAR();   // s0+0
    STAGE6(s0 + 3, 0); VM6(); BAR(); READX(2); MFMAY(); BAR();   // s0+1
    STAGE6(s0 + 4, 1); VM6(); BAR(); READY(0); MFMAX(); BAR();   // s0+2
    STAGE6(s0 + 5, 2); VM6(); BAR(); READX(1); MFMAY(); BAR();   // s0+3
    STAGE6(s0 + 6, 0); VM6(); BAR(); READY(2); MFMAX(); BAR();   // s0+4
    STAGE6(s0 + 7, 1); VM6(); BAR(); READX(0); MFMAY(); BAR();   // s0+5
  }
  // peeled slices 60..63
  STAGE6(62, 2); VM6(); BAR(); READY(1); MFMAX(); BAR();         // s=60
  STAGE6(63, 0); VM6(); BAR(); READX(2); MFMAY(); BAR();         // s=61
  VM0(); BAR(); READY(0); MFMAX(); BAR();                        // s=62
  MFMAY();                                                       // s=63
  BAR();                                                         // epi boundary
#undef STAGE6
#undef READX
#undef READY
#undef MM1
#undef MFMAX
#undef MFMAY
#undef VM6
#undef VM0
#undef BAR

  // ---- fused ON-LSTM epilogue: 2 row-passes, epi = f32[128][128] (64 KB).
  // Pass p: waves wm==p write their 128x64 tile (rows i*16+r16*4+r, cols
  // wn*64+j*16+c16); consumer: each thread 4 items -> v4f h/c stores
  // (128-B contiguous lines; r11-proven WRITE=64MB). Literal acc indices.
  float* epi = (float*)smem;
#define EPIPASS(p) do {                                                \
    if (wm == (p)) {                                                   \
      _Pragma("unroll")                                                \
      for (int i = 0; i < 8; ++i)                                      \
        _Pragma("unroll")                                              \
        for (int j = 0; j < 4; ++j)                                    \
          _Pragma("unroll")                                            \
          for (int r = 0; r < 4; ++r) {                                \
            float v = acc[i][j][r];                                    \
            v = ((c16 & 3) == 3) ? ftanhf(v) : fsig(v);                \
            epi[(i * 16 + r16 * 4 + r) * 128 + wn * 64 + j * 16 + c16] = v; \
          }                                                            \
    }                                                                  \
    __syncthreads();                                                   \
    _Pragma("unroll")                                                  \
    for (int e = 0; e < 4; ++e) {                                      \
      int idx = (e << 8) + tid;                                        \
      int mrow = idx >> 3, q = idx & 7;                                \
      const float* g4 = epi + mrow * 128 + q * 16;                     \
      int rowg = rm * 256 + (p) * 128 + mrow;                          \
      int jgb = cm * 32 + q * 4;                                       \
      int lv = jgb >> 4;                                               \
      float vih = ihp[(rowg << 6) + lv], vfh = fhp[(rowg << 6) + lv];  \
      float wq = vih * vfh;                                            \
      v4f cp4 = *(const v4f*)(cprev + rowg * 1024 + jgb);              \
      float cpv[4] = {cp4.x, cp4.y, cp4.z, cp4.w};                     \
      v4f hv, cv;                                                      \
      _Pragma("unroll")                                                \
      for (int t = 0; t < 4; ++t) {                                    \
        v4f g = *(const v4f*)(g4 + t * 4);                             \
        float iv = g.x, fv = g.y, ov = g.z, gv = g.w;                  \
        float cpx = cpv[t];                                            \
        float c = wq * (fv * cpx + iv * gv) + (vfh - wq) * cpx + (vih - wq) * gv; \
        float h = ov * ftanhf(c);                                      \
        hv[t] = h; cv[t] = c;                                          \
      }                                                                \
      *(v4f*)(out + rowg * 1024 + jgb) = hv;                           \
      *(v4f*)(out + 8388608 + rowg * 1024 + jgb) = cv;                 \
    }                                                                  \
    __syncthreads();                                                   \
  } while (0)
  EPIPASS(0); EPIPASS(1);
#undef EPIPASS
}

// -------------------------------------------------------------- launcher ---
extern "C" void kernel_launch(void* const* d_in, const int* in_sizes, int n_in,
                              void* d_out, int out_size, void* d_ws, size_t ws_size,
                              hipStream_t stream) {
  (void)in_sizes; (void)n_in; (void)out_size; (void)ws_size;
  const float* inp   = (const float*)d_in[0];
  const float* hprev = (const float*)d_in[1];
  const float* cprev = (const float*)d_in[2];
  const float* wl    = (const float*)d_in[3];
  const float* wlev  = (const float*)d_in[4];
  float* out = (float*)d_out;
  char* ws = (char*)d_ws;

  u16* Ahi  = (u16*)(ws);
  u16* Alo  = (u16*)(ws + 33554432);
  u16* Whi  = (u16*)(ws + 67108864);
  u16* Wlo  = (u16*)(ws + 84410368);
  float* part = (float*)(ws + 84934656);
  float* ih   = (float*)(ws + 118489088);
  float* fh   = (float*)(ws + 120586240);

  k_convert<<<dim3(2048), dim3(256), 0, stream>>>(inp, hprev, wl, wlev, Ahi, Alo, Whi, Wlo);
  k_gemm_level<<<dim3(64, 8), dim3(256), 0, stream>>>(Ahi, Alo, Whi, Wlo, part);
  k_softmax<<<dim3(2048), dim3(256), 0, stream>>>(part, ih, fh);
  k_gemm_main<<<dim3(1024), dim3(256), 0, stream>>>(Ahi, Whi, cprev, ih, fh, out);
}

// Round 14
// 209.750 us; speedup vs baseline: 1.1682x; 1.1682x over previous
//
#include <hip/hip_runtime.h>

// OnLSTMCell fused pipeline for MI355X (gfx950).
// B=8192, input=1024, hidden=1024, level=64, d_in=2048.
// ws layout (bytes):
//   A_HI   @ 0          : u16[8192*2048]  (32 MB)   bf16(concat(input,h_prev))
//   (A_LO region unused since r14 — dropped, error budget analysis in notes)
//   W_HI   @ 67108864   : u16[4224*2048]  (16.5 MB) rows 0..4095 gate-interleaved (n=j*4+gate), 4096..4223 = W_level
//   WLEV_LO@ 84410368   : u16[128*2048]   (0.5 MB)
//   PART   @ 84934656   : f32[8][8192][128] (32 MB) split-K partials of level GEMM
//   IH     @ 118489088  : f32[8192*64]    (2 MB)
//   FH     @ 120586240  : f32[8192*64]    (2 MB)

typedef unsigned short u16;
typedef __attribute__((ext_vector_type(8))) short bf16x8;
typedef __attribute__((ext_vector_type(8))) short s8v;
typedef __attribute__((ext_vector_type(4))) float f32x4;
typedef __attribute__((ext_vector_type(4))) float v4f;

#define GLDS(g, l) __builtin_amdgcn_global_load_lds(                      \
    (const __attribute__((address_space(1))) void*)(g),                   \
    (__attribute__((address_space(3))) void*)(l), 16, 0, 0)

__device__ __forceinline__ u16 f2bf(float x) {
  unsigned u = __builtin_bit_cast(unsigned, x);
  u += 0x7FFFu + ((u >> 16) & 1u);
  return (u16)(u >> 16);
}
__device__ __forceinline__ float bf2f(u16 h) {
  unsigned u = ((unsigned)h) << 16;
  return __builtin_bit_cast(float, u);
}
__device__ __forceinline__ float fsig(float x) { return 1.0f / (1.0f + __expf(-x)); }
__device__ __forceinline__ float ftanhf(float x) { float e = __expf(2.0f * x); return 1.0f - 2.0f / (e + 1.0f); }

// ---------------------------------------------------------------- convert ---
// r14: A path writes HI only (A_LO dropped — the level GEMM's missing
// Alo*B term adds ~1.6e-3 std on unit-std logits, well inside budget).
__global__ __launch_bounds__(256) void k_convert(
    const float* __restrict__ inp, const float* __restrict__ hprev,
    const float* __restrict__ wl, const float* __restrict__ wlev,
    u16* __restrict__ Ahi, u16* __restrict__ Whi, u16* __restrict__ Wlo)
{
  const int GA = (8192 * 2048) / 8;
  const int GW = (4224 * 2048) / 8;
  for (int gi = blockIdx.x * 256 + threadIdx.x; gi < GA + GW; gi += gridDim.x * 256) {
    if (gi < GA) {
      int e = gi << 3; int row = e >> 11, col = e & 2047;
      const float* src = (col < 1024) ? (inp + row * 1024 + col)
                                      : (hprev + row * 1024 + (col - 1024));
      v4f a = *(const v4f*)src, b = *(const v4f*)(src + 4);
      float vv[8] = {a.x, a.y, a.z, a.w, b.x, b.y, b.z, b.w};
      s8v hi;
#pragma unroll
      for (int j = 0; j < 8; ++j) hi[j] = (short)f2bf(vv[j]);
      *(s8v*)(Ahi + e) = hi;
    } else {
      int e = (gi - GA) << 3; int n = e >> 11, k = e & 2047;
      const float* src;
      if (n < 4096) { int j = n >> 2, g = n & 3; src = wl + (size_t)((g << 10) | j) * 2048 + k; }
      else          { src = wlev + (size_t)(n - 4096) * 2048 + k; }
      v4f a = *(const v4f*)src, b = *(const v4f*)(src + 4);
      float vv[8] = {a.x, a.y, a.z, a.w, b.x, b.y, b.z, b.w};
      s8v hi, lo;
#pragma unroll
      for (int j = 0; j < 8; ++j) {
        u16 h = f2bf(vv[j]);
        hi[j] = (short)h;
        lo[j] = (short)f2bf(vv[j] - bf2f(h));
      }
      *(s8v*)(Whi + e) = hi;
      if (n >= 4096) *(s8v*)(Wlo + (size_t)(n - 4096) * 2048 + k) = lo;
    }
  }
}

// ----------------------------------------------- level GEMM (2-pass bf16) ---
// r14: Ah*(Bh + Bl) — A_LO pass dropped. LDS 48 KB (Ah|Bh|Bl), 3 GLDS/q,
// 2 MFMA per (i,j) pair.
__global__ __launch_bounds__(256) void k_gemm_level(
    const u16* __restrict__ Ahi, const u16* __restrict__ Whi,
    const u16* __restrict__ Wlo, float* __restrict__ part)
{
  __shared__ __align__(16) u16 smem[3 * 8192];
  u16 *Ah = smem, *Bh = smem + 8192, *Bl = smem + 16384;
  const int tid = threadIdx.x, lane = tid & 63, wid = tid >> 6;
  const int wm = wid >> 1, wn = wid & 1;
  const int rm = blockIdx.x, s = blockIdx.y;
  const int lrow = lane >> 3, lcolE = (lane & 7) << 3;
  const int c16 = lane & 15, r16 = lane >> 4;
  f32x4 acc[4][4] = {};
  const u16* aBaseH = Ahi + (size_t)(rm << 7) * 2048;
  const u16* bBaseH = Whi + (size_t)4096 * 2048;

  for (int kt = 0; kt < 4; ++kt) {
    const int k0 = (s << 8) + (kt << 6);
#pragma unroll
    for (int q = 0; q < 4; ++q) {
      const int ca = (wid << 2) + q;
      size_t roff = (size_t)((ca << 3) + lrow) * 2048 + k0 + lcolE;
      GLDS(aBaseH + roff, Ah + (ca << 9));
      GLDS(bBaseH + roff, Bh + (ca << 9));
      GLDS(Wlo + roff,    Bl + (ca << 9));
    }
    __syncthreads();
#pragma unroll
    for (int ks = 0; ks < 2; ++ks) {
      bf16x8 ah[4];
#pragma unroll
      for (int i = 0; i < 4; ++i) {
        int off = ((wm << 6) + (i << 4) + c16) * 64 + (ks << 5) + (r16 << 3);
        ah[i] = *(const bf16x8*)(Ah + off);
      }
#pragma unroll
      for (int j = 0; j < 4; ++j) {
        int off = ((wn << 6) + (j << 4) + c16) * 64 + (ks << 5) + (r16 << 3);
        bf16x8 bh = *(const bf16x8*)(Bh + off);
        bf16x8 bl = *(const bf16x8*)(Bl + off);
#pragma unroll
        for (int i = 0; i < 4; ++i) {
          acc[i][j] = __builtin_amdgcn_mfma_f32_16x16x32_bf16(ah[i], bh, acc[i][j], 0, 0, 0);
          acc[i][j] = __builtin_amdgcn_mfma_f32_16x16x32_bf16(ah[i], bl, acc[i][j], 0, 0, 0);
        }
      }
    }
    __syncthreads();
  }
#pragma unroll
  for (int mi = 0; mi < 4; ++mi)
#pragma unroll
    for (int ni = 0; ni < 4; ++ni)
#pragma unroll
      for (int r = 0; r < 4; ++r) {
        int ml = (wm << 6) + (mi << 4) + (r16 << 2) + r;
        int nl = (wn << 6) + (ni << 4) + c16;
        part[(size_t)((s << 13) + (rm << 7) + ml) * 128 + nl] = acc[mi][ni][r];
      }
}

// ------------------------------------------- softmax + cumsums (per row) ---
__global__ __launch_bounds__(256) void k_softmax(
    const float* __restrict__ part, float* __restrict__ ih, float* __restrict__ fh)
{
  const int tid = threadIdx.x, lane = tid & 63, w = tid >> 6;
  const int row = blockIdx.x * 4 + w;
  float vi = 0.f, vf = 0.f;
#pragma unroll
  for (int s = 0; s < 8; ++s) {
    vi += part[(size_t)((s << 13) + row) * 128 + lane];
    vf += part[(size_t)((s << 13) + row) * 128 + 64 + lane];
  }
  float mi = vi, mf = vf;
#pragma unroll
  for (int d = 1; d < 64; d <<= 1) {
    mi = fmaxf(mi, __shfl_xor(mi, d, 64));
    mf = fmaxf(mf, __shfl_xor(mf, d, 64));
  }
  float ei = __expf(vi - mi), ef = __expf(vf - mf);
  float si = ei, sf = ef;
#pragma unroll
  for (int d = 1; d < 64; d <<= 1) {
    si += __shfl_xor(si, d, 64);
    sf += __shfl_xor(sf, d, 64);
  }
  float pi = ei / si, pf = ef / sf;
  float ci = pi, cf = pf;
#pragma unroll
  for (int d = 1; d < 64; d <<= 1) {
    float t = __shfl_up(ci, d, 64); if (lane >= d) ci += t;
    float u = __shfl_up(cf, d, 64); if (lane >= d) cf += u;
  }
  ih[(row << 6) + lane] = 1.0f - (ci - pi);
  fh[(row << 6) + lane] = cf;
}

// -------------------------------------- main gates GEMM + fused epilogue ---
// r12 VERBATIM (best verified: 167us, MfmaUtil 37%, VGPR 64): 256x128 tile,
// 8 waves 4Mx2N (64x64 wave-tiles, FLOP/LDS-byte=32), 3-slot 72KB LDS ->
// 2 blocks/CU, cm-fast XCD map, vmcnt(3) ledger, NO setprio, coalesced
// v4f epilogue. r13's reg-double-buffer (256thr) regressed (199us): halved
// waves/CU beat the in-wave overlap it bought — reverted.
__global__ __launch_bounds__(512, 4) void k_gemm_main(
    const u16* __restrict__ Ab, const u16* __restrict__ Wb,
    const float* __restrict__ cprev, const float* __restrict__ ihp,
    const float* __restrict__ fhp, float* __restrict__ out)
{
  __shared__ __align__(16) u16 smem[36864];        // 72 KB; epi reuses 64 KB
  const int tid = threadIdx.x, lane = tid & 63, wid = tid >> 6;
  const int wm = wid >> 1, wn = wid & 1;           // 4M x 2N wave grid
  const int c16 = lane & 15, r16 = lane >> 4;

  // cm-FAST XCD swizzle: 1024 blocks = 8 XCD x 128 = 4 rm-panels
  // (A L2-resident) x 32 cm (W streamed, L3-absorbed).
  const int bx = blockIdx.x;
  const int nb = (bx & 7) * 128 + (bx >> 3);
  const int rm = nb >> 5, cm = nb & 31;            // rm slow, cm fast

  // staging: thread -> (row sr=tid>>2, 16B slot slq=tid&3); global source
  // pre-permuted (slq ^ (sr>>1)&3) so linear GLDS dest gets the swizzle.
  const int sr = tid >> 2;                          // 0..127
  const int slq = tid & 3;
  const int xk = (slq ^ ((sr >> 1) & 3)) << 3;
  const u16* pa = Ab + (size_t)(rm * 256 + sr) * 2048 + xk;
  const u16* pb = Wb + (size_t)(cm * 128 + sr) * 2048 + xk;
  char* const ldsW = (char*)smem + (wid << 10);     // wave segment (1 KB)

  // ds_read offsets (u16 elements): slot base + row*32 + swizzled 16B slot.
  const int xsl = (r16 ^ ((c16 >> 1) & 3)) << 3;
  const int base_a = (wm * 64 + c16) * 32 + xsl;        // + i*512 (i=0..3)
  const int base_b = 8192 + (wn * 64 + c16) * 32 + xsl; // + j*512 (j=0..3)

  f32x4 acc[4][4] = {};

#define STAGE3(slice, slot) do {                                       \
    const u16* sa_ = pa + (slice) * 32;                                \
    const u16* sb_ = pb + (slice) * 32;                                \
    char* d_ = ldsW + (slot) * 24576;                                  \
    GLDS(sa_, d_); GLDS(sa_ + 262144, d_ + 8192);                      \
    GLDS(sb_, d_ + 16384);                                             \
  } while (0)

#define SLICE(s, slot, dostage) do {                                   \
    bf16x8 aX[4], bS[4];                                               \
    _Pragma("unroll")                                                  \
    for (int i = 0; i < 4; ++i)                                        \
      aX[i] = *(const bf16x8*)(smem + (slot) * 12288 + base_a + i * 512); \
    _Pragma("unroll")                                                  \
    for (int j = 0; j < 4; ++j)                                        \
      bS[j] = *(const bf16x8*)(smem + (slot) * 12288 + base_b + j * 512); \
    if (dostage) STAGE3(((s) + 2) & 63, ((s) + 2) % 3);                \
    asm volatile("s_waitcnt vmcnt(3)" ::: "memory");                   \
    __builtin_amdgcn_s_barrier();                                      \
    asm volatile("s_waitcnt lgkmcnt(0)" ::: "memory");                 \
    _Pragma("unroll")                                                  \
    for (int i = 0; i < 4; ++i)                                        \
      _Pragma("unroll")                                                \
      for (int j = 0; j < 4; ++j)                                      \
        acc[i][j] = __builtin_amdgcn_mfma_f32_16x16x32_bf16(           \
            aX[i], bS[j], acc[i][j], 0, 0, 0);                         \
    __builtin_amdgcn_s_barrier();                                      \
  } while (0)

  // prologue: slices 0,1 -> slots 0,1; vmcnt(3) forces slice 0 complete
  // (leaves slice 1 in flight); barrier publishes to all waves.
  STAGE3(0, 0); STAGE3(1, 1);
  asm volatile("s_waitcnt vmcnt(3)" ::: "memory");
  __builtin_amdgcn_s_barrier();

  for (int u = 0; u < 21; ++u) {                    // slices 0..62
    const int s0 = u * 3;
    SLICE(s0 + 0, 0, 1);
    SLICE(s0 + 1, 1, 1);
    SLICE(s0 + 2, 2, 1);
  }
  SLICE(63, 0, 0);                                  // peeled last slice
#undef SLICE
#undef STAGE3

  // drain wrap-dummy stages before LDS reuse
  asm volatile("s_waitcnt vmcnt(0)" ::: "memory");
  __builtin_amdgcn_s_barrier();

  // ---- fused ON-LSTM epilogue: 2 row-passes, epi = f32[128][128] (64 KB).
  float* epi = (float*)smem;
#define EPIPASS(p) do {                                                \
    if ((wm >> 1) == (p)) {                                            \
      _Pragma("unroll")                                                \
      for (int i = 0; i < 4; ++i)                                      \
        _Pragma("unroll")                                              \
        for (int j = 0; j < 4; ++j)                                    \
          _Pragma("unroll")                                            \
          for (int r = 0; r < 4; ++r) {                                \
            float v = acc[i][j][r];                                    \
            v = ((c16 & 3) == 3) ? ftanhf(v) : fsig(v);                \
            epi[((wm & 1) * 64 + i * 16 + r16 * 4 + r) * 128 +         \
                wn * 64 + j * 16 + c16] = v;                           \
          }                                                            \
    }                                                                  \
    __syncthreads();                                                   \
    _Pragma("unroll")                                                  \
    for (int e = 0; e < 2; ++e) {                                      \
      int idx = (e << 9) + tid;                                        \
      int mrow = idx >> 3, q = idx & 7;                                \
      const float* g4 = epi + mrow * 128 + q * 16;                     \
      int rowg = rm * 256 + (p) * 128 + mrow;                          \
      int jgb = cm * 32 + q * 4;                                       \
      int lv = jgb >> 4;                                               \
      float vih = ihp[(rowg << 6) + lv], vfh = fhp[(rowg << 6) + lv];  \
      float wq = vih * vfh;                                            \
      v4f cp4 = *(const v4f*)(cprev + rowg * 1024 + jgb);              \
      float cpv[4] = {cp4.x, cp4.y, cp4.z, cp4.w};                     \
      v4f hv, cv;                                                      \
      _Pragma("unroll")                                                \
      for (int t = 0; t < 4; ++t) {                                    \
        v4f g = *(const v4f*)(g4 + t * 4);                             \
        float iv = g.x, fv = g.y, ov = g.z, gv = g.w;                  \
        float cpx = cpv[t];                                            \
        float c = wq * (fv * cpx + iv * gv) + (vfh - wq) * cpx + (vih - wq) * gv; \
        float h = ov * ftanhf(c);                                      \
        hv[t] = h; cv[t] = c;                                          \
      }                                                                \
      *(v4f*)(out + rowg * 1024 + jgb) = hv;                           \
      *(v4f*)(out + 8388608 + rowg * 1024 + jgb) = cv;                 \
    }                                                                  \
    __syncthreads();                                                   \
  } while (0)
  EPIPASS(0); EPIPASS(1);
#undef EPIPASS
}

// -------------------------------------------------------------- launcher ---
extern "C" void kernel_launch(void* const* d_in, const int* in_sizes, int n_in,
                              void* d_out, int out_size, void* d_ws, size_t ws_size,
                              hipStream_t stream) {
  (void)in_sizes; (void)n_in; (void)out_size; (void)ws_size;
  const float* inp   = (const float*)d_in[0];
  const float* hprev = (const float*)d_in[1];
  const float* cprev = (const float*)d_in[2];
  const float* wl    = (const float*)d_in[3];
  const float* wlev  = (const float*)d_in[4];
  float* out = (float*)d_out;
  char* ws = (char*)d_ws;

  u16* Ahi  = (u16*)(ws);
  u16* Whi  = (u16*)(ws + 67108864);
  u16* Wlo  = (u16*)(ws + 84410368);
  float* part = (float*)(ws + 84934656);
  float* ih   = (float*)(ws + 118489088);
  float* fh   = (float*)(ws + 120586240);

  k_convert<<<dim3(2048), dim3(256), 0, stream>>>(inp, hprev, wl, wlev, Ahi, Whi, Wlo);
  k_gemm_level<<<dim3(64, 8), dim3(256), 0, stream>>>(Ahi, Whi, Wlo, part);
  k_softmax<<<dim3(2048), dim3(256), 0, stream>>>(part, ih, fh);
  k_gemm_main<<<dim3(1024), dim3(512), 0, stream>>>(Ahi, Whi, cprev, ih, fh, out);
}

// Round 15
// 204.068 us; speedup vs baseline: 1.2008x; 1.0278x over previous
//
#include <hip/hip_runtime.h>

// OnLSTMCell fused pipeline for MI355X (gfx950).
// B=8192, input=1024, hidden=1024, level=64, d_in=2048.
// ws layout (bytes):
//   A_HI   @ 0          : u16[8192*2048]  (32 MB)   bf16(concat(input,h_prev))
//   W_HI   @ 67108864   : u16[4224*2048]  (16.5 MB) rows 0..4095 gate-interleaved (n=j*4+gate), 4096..4223 = W_level
//   WLEV_LO@ 84410368   : u16[128*2048]   (0.5 MB)
//   IH     @ 118489088  : f32[8192*64]    (2 MB)
//   FH     @ 120586240  : f32[8192*64]    (2 MB)
// (PART region unused since r15 — level GEMM + softmax fused, full-K.)

typedef unsigned short u16;
typedef __attribute__((ext_vector_type(8))) short bf16x8;
typedef __attribute__((ext_vector_type(8))) short s8v;
typedef __attribute__((ext_vector_type(4))) float f32x4;
typedef __attribute__((ext_vector_type(4))) float v4f;

#define GLDS(g, l) __builtin_amdgcn_global_load_lds(                      \
    (const __attribute__((address_space(1))) void*)(g),                   \
    (__attribute__((address_space(3))) void*)(l), 16, 0, 0)

__device__ __forceinline__ u16 f2bf(float x) {
  unsigned u = __builtin_bit_cast(unsigned, x);
  u += 0x7FFFu + ((u >> 16) & 1u);
  return (u16)(u >> 16);
}
__device__ __forceinline__ float bf2f(u16 h) {
  unsigned u = ((unsigned)h) << 16;
  return __builtin_bit_cast(float, u);
}
__device__ __forceinline__ float fsig(float x) { return 1.0f / (1.0f + __expf(-x)); }
__device__ __forceinline__ float ftanhf(float x) { float e = __expf(2.0f * x); return 1.0f - 2.0f / (e + 1.0f); }

// ---------------------------------------------------------------- convert ---
// (unchanged from r14)
__global__ __launch_bounds__(256) void k_convert(
    const float* __restrict__ inp, const float* __restrict__ hprev,
    const float* __restrict__ wl, const float* __restrict__ wlev,
    u16* __restrict__ Ahi, u16* __restrict__ Whi, u16* __restrict__ Wlo)
{
  const int GA = (8192 * 2048) / 8;
  const int GW = (4224 * 2048) / 8;
  for (int gi = blockIdx.x * 256 + threadIdx.x; gi < GA + GW; gi += gridDim.x * 256) {
    if (gi < GA) {
      int e = gi << 3; int row = e >> 11, col = e & 2047;
      const float* src = (col < 1024) ? (inp + row * 1024 + col)
                                      : (hprev + row * 1024 + (col - 1024));
      v4f a = *(const v4f*)src, b = *(const v4f*)(src + 4);
      float vv[8] = {a.x, a.y, a.z, a.w, b.x, b.y, b.z, b.w};
      s8v hi;
#pragma unroll
      for (int j = 0; j < 8; ++j) hi[j] = (short)f2bf(vv[j]);
      *(s8v*)(Ahi + e) = hi;
    } else {
      int e = (gi - GA) << 3; int n = e >> 11, k = e & 2047;
      const float* src;
      if (n < 4096) { int j = n >> 2, g = n & 3; src = wl + (size_t)((g << 10) | j) * 2048 + k; }
      else          { src = wlev + (size_t)(n - 4096) * 2048 + k; }
      v4f a = *(const v4f*)src, b = *(const v4f*)(src + 4);
      float vv[8] = {a.x, a.y, a.z, a.w, b.x, b.y, b.z, b.w};
      s8v hi, lo;
#pragma unroll
      for (int j = 0; j < 8; ++j) {
        u16 h = f2bf(vv[j]);
        hi[j] = (short)h;
        lo[j] = (short)f2bf(vv[j] - bf2f(h));
      }
      *(s8v*)(Whi + e) = hi;
      if (n >= 4096) *(s8v*)(Wlo + (size_t)(n - 4096) * 2048 + k) = lo;
    }
  }
}

// ------------------- level GEMM + softmax + cumsums, fused (full-K) ---------
// 256 blocks x 256 thr (4 waves). Block: rows r0=bid*32, cols 128 (W_level),
// K=2048 full (32 tiles of BK=64) -> logits in acc, then softmax+cumsum in
// epilogue. Eliminates PART (64 MB round-trip) and the k_softmax launch.
// W split-bf16 kept: out = Ah*(Bh + Bl).
// LDS: 2 bufs x {A 32x64 (4KB) | Bh 128x64 (16KB) | Bl (16KB)} = 72 KB
// -> 2 blocks/CU. Double-buffered, counted vmcnt(9) (9 GLDS/stage/wave):
// at tile t, outstanding = stage(t)(9) + stage(t+1)(9) -> vmcnt(9) forces
// stage(t) before the barrier preceding its reads; WAR: stage(t+1)
// overwrites buf read at t-1 (published by t-1's end barrier). vmcnt(0)
// only at peeled t=31.
// Swizzle: 128-B rows = 8 16-B slots; slot' = slot ^ (row&7) both sides
// (stage src pre-permuted, read XORs) -> 16 lanes spread over 8 bank
// groups = 2-way, free. (Old k_gemm_level was un-swizzled 16-way.)
__global__ __launch_bounds__(256) void k_level_fused(
    const u16* __restrict__ Ahi, const u16* __restrict__ Whi,
    const u16* __restrict__ Wlo, float* __restrict__ ih, float* __restrict__ fh)
{
  __shared__ __align__(16) u16 smem[2 * 18432];   // 72 KB
  const int tid = threadIdx.x, lane = tid & 63, wid = tid >> 6;
  const int c16 = lane & 15, r16 = lane >> 4;
  const int r0 = blockIdx.x << 5;

  // staging: thread t -> row=t>>3, slot=t&7; src k pre-permuted by row&7.
  const int row_t = tid >> 3;
  const int xk8 = ((tid & 7) ^ (row_t & 7)) << 3;
  const u16* pa_s  = Ahi + (size_t)(r0 + row_t) * 2048 + xk8;
  const u16* pbh_s = Whi + (size_t)(4096 + row_t) * 2048 + xk8;
  const u16* pbl_s = Wlo + (size_t)row_t * 2048 + xk8;
  char* const ldsW = (char*)smem + (wid << 10);   // wave segment per 4KB pass

  // read slot terms (u16 elems): slot' = ((ks<<2)|r16) ^ (c16&7)
  const int sl0 = ((r16 ^ (c16 & 7)) << 3);
  const int sl1 = (((4 | r16) ^ (c16 & 7)) << 3);

  f32x4 acc[2][2] = {};

#define LSTAGE(kt, buf) do {                                           \
    char* d_ = ldsW + (buf) * 36864;                                   \
    const int ko_ = (kt) * 64;                                         \
    GLDS(pa_s + ko_, d_);                                              \
    GLDS(pbh_s + ko_,          d_ + 4096);                             \
    GLDS(pbh_s + ko_ + 65536,  d_ + 8192);                             \
    GLDS(pbh_s + ko_ + 131072, d_ + 12288);                            \
    GLDS(pbh_s + ko_ + 196608, d_ + 16384);                            \
    GLDS(pbl_s + ko_,          d_ + 20480);                            \
    GLDS(pbl_s + ko_ + 65536,  d_ + 24576);                            \
    GLDS(pbl_s + ko_ + 131072, d_ + 28672);                            \
    GLDS(pbl_s + ko_ + 196608, d_ + 32768);                            \
  } while (0)

#define LCOMP(buf) do {                                                \
    const u16* bp_ = smem + (buf) * 18432;                             \
    _Pragma("unroll")                                                  \
    for (int ks = 0; ks < 2; ++ks) {                                   \
      const int sx_ = ks ? sl1 : sl0;                                  \
      bf16x8 ah[2];                                                    \
      _Pragma("unroll")                                                \
      for (int mi = 0; mi < 2; ++mi)                                   \
        ah[mi] = *(const bf16x8*)(bp_ + (mi * 16 + c16) * 64 + sx_);   \
      _Pragma("unroll")                                                \
      for (int j = 0; j < 2; ++j) {                                    \
        int br_ = (wid * 32 + j * 16 + c16) * 64 + sx_;                \
        bf16x8 bh = *(const bf16x8*)(bp_ + 2048 + br_);                \
        bf16x8 bl = *(const bf16x8*)(bp_ + 10240 + br_);               \
        _Pragma("unroll")                                              \
        for (int mi = 0; mi < 2; ++mi) {                               \
          acc[mi][j] = __builtin_amdgcn_mfma_f32_16x16x32_bf16(ah[mi], bh, acc[mi][j], 0, 0, 0); \
          acc[mi][j] = __builtin_amdgcn_mfma_f32_16x16x32_bf16(ah[mi], bl, acc[mi][j], 0, 0, 0); \
        }                                                              \
      }                                                                \
    }                                                                  \
  } while (0)

#define LTILE(t, buf, dostage) do {                                    \
    if (dostage) LSTAGE((t) + 1, (buf) ^ 1);                           \
    if (dostage) asm volatile("s_waitcnt vmcnt(9)" ::: "memory");      \
    else         asm volatile("s_waitcnt vmcnt(0)" ::: "memory");      \
    __builtin_amdgcn_s_barrier();                                      \
    LCOMP(buf);                                                        \
    __builtin_amdgcn_s_barrier();                                      \
  } while (0)

  LSTAGE(0, 0);
  for (int u = 0; u < 15; ++u) {                   // tiles 0..29
    LTILE(2 * u, 0, 1);
    LTILE(2 * u + 1, 1, 1);
  }
  LTILE(30, 0, 1);
  LTILE(31, 1, 0);
#undef LTILE
#undef LCOMP
#undef LSTAGE

  // ---- epilogue: logits -> LDS, per-row dual softmax + cumsums ----
  float* epi = (float*)smem;                       // 32 x 128 f32 = 16 KB
#pragma unroll
  for (int mi = 0; mi < 2; ++mi)
#pragma unroll
    for (int j = 0; j < 2; ++j)
#pragma unroll
      for (int r = 0; r < 4; ++r)
        epi[(mi * 16 + r16 * 4 + r) * 128 + wid * 32 + j * 16 + c16] = acc[mi][j][r];
  __syncthreads();

  for (int rr = 0; rr < 8; ++rr) {
    int row = wid * 8 + rr;
    float vi = epi[row * 128 + lane];
    float vf = epi[row * 128 + 64 + lane];
    float mi = vi, mf = vf;
#pragma unroll
    for (int d = 1; d < 64; d <<= 1) {
      mi = fmaxf(mi, __shfl_xor(mi, d, 64));
      mf = fmaxf(mf, __shfl_xor(mf, d, 64));
    }
    float ei = __expf(vi - mi), ef = __expf(vf - mf);
    float si = ei, sf = ef;
#pragma unroll
    for (int d = 1; d < 64; d <<= 1) {
      si += __shfl_xor(si, d, 64);
      sf += __shfl_xor(sf, d, 64);
    }
    float pi = ei / si, pf = ef / sf;
    float ci = pi, cf = pf;
#pragma unroll
    for (int d = 1; d < 64; d <<= 1) {
      float t = __shfl_up(ci, d, 64); if (lane >= d) ci += t;
      float uu = __shfl_up(cf, d, 64); if (lane >= d) cf += uu;
    }
    int rowg = r0 + row;
    ih[(rowg << 6) + lane] = 1.0f - (ci - pi);     // reverse cumsum of p_i
    fh[(rowg << 6) + lane] = cf;                   // forward cumsum of p_f
  }
}

// -------------------------------------- main gates GEMM + fused epilogue ---
// r12/r14 VERBATIM (best verified: 167us, MfmaUtil 37%, VGPR 64).
__global__ __launch_bounds__(512, 4) void k_gemm_main(
    const u16* __restrict__ Ab, const u16* __restrict__ Wb,
    const float* __restrict__ cprev, const float* __restrict__ ihp,
    const float* __restrict__ fhp, float* __restrict__ out)
{
  __shared__ __align__(16) u16 smem[36864];        // 72 KB; epi reuses 64 KB
  const int tid = threadIdx.x, lane = tid & 63, wid = tid >> 6;
  const int wm = wid >> 1, wn = wid & 1;           // 4M x 2N wave grid
  const int c16 = lane & 15, r16 = lane >> 4;

  const int bx = blockIdx.x;
  const int nb = (bx & 7) * 128 + (bx >> 3);
  const int rm = nb >> 5, cm = nb & 31;            // rm slow, cm fast

  const int sr = tid >> 2;
  const int slq = tid & 3;
  const int xk = (slq ^ ((sr >> 1) & 3)) << 3;
  const u16* pa = Ab + (size_t)(rm * 256 + sr) * 2048 + xk;
  const u16* pb = Wb + (size_t)(cm * 128 + sr) * 2048 + xk;
  char* const ldsW = (char*)smem + (wid << 10);

  const int xsl = (r16 ^ ((c16 >> 1) & 3)) << 3;
  const int base_a = (wm * 64 + c16) * 32 + xsl;
  const int base_b = 8192 + (wn * 64 + c16) * 32 + xsl;

  f32x4 acc[4][4] = {};

#define STAGE3(slice, slot) do {                                       \
    const u16* sa_ = pa + (slice) * 32;                                \
    const u16* sb_ = pb + (slice) * 32;                                \
    char* d_ = ldsW + (slot) * 24576;                                  \
    GLDS(sa_, d_); GLDS(sa_ + 262144, d_ + 8192);                      \
    GLDS(sb_, d_ + 16384);                                             \
  } while (0)

#define SLICE(s, slot, dostage) do {                                   \
    bf16x8 aX[4], bS[4];                                               \
    _Pragma("unroll")                                                  \
    for (int i = 0; i < 4; ++i)                                        \
      aX[i] = *(const bf16x8*)(smem + (slot) * 12288 + base_a + i * 512); \
    _Pragma("unroll")                                                  \
    for (int j = 0; j < 4; ++j)                                        \
      bS[j] = *(const bf16x8*)(smem + (slot) * 12288 + base_b + j * 512); \
    if (dostage) STAGE3(((s) + 2) & 63, ((s) + 2) % 3);                \
    asm volatile("s_waitcnt vmcnt(3)" ::: "memory");                   \
    __builtin_amdgcn_s_barrier();                                      \
    asm volatile("s_waitcnt lgkmcnt(0)" ::: "memory");                 \
    _Pragma("unroll")                                                  \
    for (int i = 0; i < 4; ++i)                                        \
      _Pragma("unroll")                                                \
      for (int j = 0; j < 4; ++j)                                      \
        acc[i][j] = __builtin_amdgcn_mfma_f32_16x16x32_bf16(           \
            aX[i], bS[j], acc[i][j], 0, 0, 0);                         \
    __builtin_amdgcn_s_barrier();                                      \
  } while (0)

  STAGE3(0, 0); STAGE3(1, 1);
  asm volatile("s_waitcnt vmcnt(3)" ::: "memory");
  __builtin_amdgcn_s_barrier();

  for (int u = 0; u < 21; ++u) {                    // slices 0..62
    const int s0 = u * 3;
    SLICE(s0 + 0, 0, 1);
    SLICE(s0 + 1, 1, 1);
    SLICE(s0 + 2, 2, 1);
  }
  SLICE(63, 0, 0);                                  // peeled last slice
#undef SLICE
#undef STAGE3

  asm volatile("s_waitcnt vmcnt(0)" ::: "memory");
  __builtin_amdgcn_s_barrier();

  float* epi = (float*)smem;
#define EPIPASS(p) do {                                                \
    if ((wm >> 1) == (p)) {                                            \
      _Pragma("unroll")                                                \
      for (int i = 0; i < 4; ++i)                                      \
        _Pragma("unroll")                                              \
        for (int j = 0; j < 4; ++j)                                    \
          _Pragma("unroll")                                            \
          for (int r = 0; r < 4; ++r) {                                \
            float v = acc[i][j][r];                                    \
            v = ((c16 & 3) == 3) ? ftanhf(v) : fsig(v);                \
            epi[((wm & 1) * 64 + i * 16 + r16 * 4 + r) * 128 +         \
                wn * 64 + j * 16 + c16] = v;                           \
          }                                                            \
    }                                                                  \
    __syncthreads();                                                   \
    _Pragma("unroll")                                                  \
    for (int e = 0; e < 2; ++e) {                                      \
      int idx = (e << 9) + tid;                                        \
      int mrow = idx >> 3, q = idx & 7;                                \
      const float* g4 = epi + mrow * 128 + q * 16;                     \
      int rowg = rm * 256 + (p) * 128 + mrow;                          \
      int jgb = cm * 32 + q * 4;                                       \
      int lv = jgb >> 4;                                               \
      float vih = ihp[(rowg << 6) + lv], vfh = fhp[(rowg << 6) + lv];  \
      float wq = vih * vfh;                                            \
      v4f cp4 = *(const v4f*)(cprev + rowg * 1024 + jgb);              \
      float cpv[4] = {cp4.x, cp4.y, cp4.z, cp4.w};                     \
      v4f hv, cv;                                                      \
      _Pragma("unroll")                                                \
      for (int t = 0; t < 4; ++t) {                                    \
        v4f g = *(const v4f*)(g4 + t * 4);                             \
        float iv = g.x, fv = g.y, ov = g.z, gv = g.w;                  \
        float cpx = cpv[t];                                            \
        float c = wq * (fv * cpx + iv * gv) + (vfh - wq) * cpx + (vih - wq) * gv; \
        float h = ov * ftanhf(c);                                      \
        hv[t] = h; cv[t] = c;                                          \
      }                                                                \
      *(v4f*)(out + rowg * 1024 + jgb) = hv;                           \
      *(v4f*)(out + 8388608 + rowg * 1024 + jgb) = cv;                 \
    }                                                                  \
    __syncthreads();                                                   \
  } while (0)
  EPIPASS(0); EPIPASS(1);
#undef EPIPASS
}

// -------------------------------------------------------------- launcher ---
extern "C" void kernel_launch(void* const* d_in, const int* in_sizes, int n_in,
                              void* d_out, int out_size, void* d_ws, size_t ws_size,
                              hipStream_t stream) {
  (void)in_sizes; (void)n_in; (void)out_size; (void)ws_size;
  const float* inp   = (const float*)d_in[0];
  const float* hprev = (const float*)d_in[1];
  const float* cprev = (const float*)d_in[2];
  const float* wl    = (const float*)d_in[3];
  const float* wlev  = (const float*)d_in[4];
  float* out = (float*)d_out;
  char* ws = (char*)d_ws;

  u16* Ahi  = (u16*)(ws);
  u16* Whi  = (u16*)(ws + 67108864);
  u16* Wlo  = (u16*)(ws + 84410368);
  float* ih   = (float*)(ws + 118489088);
  float* fh   = (float*)(ws + 120586240);

  k_convert<<<dim3(2048), dim3(256), 0, stream>>>(inp, hprev, wl, wlev, Ahi, Whi, Wlo);
  k_level_fused<<<dim3(256), dim3(256), 0, stream>>>(Ahi, Whi, Wlo, ih, fh);
  k_gemm_main<<<dim3(1024), dim3(512), 0, stream>>>(Ahi, Whi, cprev, ih, fh, out);
}